// Round 6
// baseline (755.292 us; speedup 1.0000x reference)
//
#include <hip/hip_runtime.h>

// Problem constants (match reference)
constexpr int NN   = 50000;          // nodes
constexpr int NE   = 800000;         // edges before self loops
constexpr int NHD  = 4;              // heads
constexpr int CC   = 32;             // channels per head
constexpr int HCC  = 128;            // NHD*CC
constexpr int NL   = 3;              // layers
constexpr int NG   = 128;            // graphs
constexpr int NOUT = 10;             // out channels
constexpr float BN_EPS = 1e-5f;

constexpr int XS = 133;              // LDS x-row stride
constexpr int YS = 33;               // LDS y-row stride

// fp32 -> bf16 (round-to-nearest-even), packed pair helpers
__device__ inline unsigned f2bf_pack(float a, float b) {
    unsigned ua = __float_as_uint(a); ua += 0x7FFFu + ((ua >> 16) & 1u);
    unsigned ub = __float_as_uint(b); ub += 0x7FFFu + ((ub >> 16) & 1u);
    return (ua >> 16) | (ub & 0xFFFF0000u);
}
__device__ inline float bf_lo(unsigned p) { return __uint_as_float(p << 16); }
__device__ inline float bf_hi(unsigned p) { return __uint_as_float(p & 0xFFFF0000u); }

// -------------------------------------- embed gather + BN stats for layer 0
__global__ __launch_bounds__(256) void k_embed_stats(const int* __restrict__ idx,
                                                     const float* __restrict__ embed,
                                                     float* __restrict__ x,
                                                     float* __restrict__ stats) {
    int i0 = blockIdx.x * 256 + threadIdx.x;
    int stride = gridDim.x * 256;                 // multiple of 128
    float s = 0.f, q = 0.f;
    for (int i = i0; i < NN * HCC; i += stride) {
        float v = embed[idx[i >> 7] * HCC + (i & 127)];
        x[i] = v; s += v; q += v * v;
    }
    __shared__ float ssum[256], ssq[256];
    ssum[threadIdx.x] = s; ssq[threadIdx.x] = q;
    __syncthreads();
    if (threadIdx.x < HCC) {
        atomicAdd(&stats[threadIdx.x],       ssum[threadIdx.x] + ssum[threadIdx.x + HCC]);
        atomicAdd(&stats[HCC + threadIdx.x], ssq[threadIdx.x]  + ssq[threadIdx.x + HCC]);
    }
}

// ------------------------------------------------------------ CSR build: degree
__global__ __launch_bounds__(256) void k_hist(const int* __restrict__ ei,
                                              int* __restrict__ deg) {
    int e = blockIdx.x * 256 + threadIdx.x;
    if (e >= NE) return;
    atomicAdd(&deg[ei[NE + e]], 1);
}

// chunked single-block exclusive scan
__global__ __launch_bounds__(1024) void k_scan(const int* __restrict__ deg,
                                               int* __restrict__ rowptr) {
    __shared__ int sh[1024];
    int tid = threadIdx.x;
    const int CH = (NN + 1023) / 1024;            // 49
    int st = tid * CH, en = min(st + CH, NN);
    int sum = 0;
    for (int i = st; i < en; i++) sum += deg[i];
    sh[tid] = sum;
    __syncthreads();
    for (int off = 1; off < 1024; off <<= 1) {
        int v = (tid >= off) ? sh[tid - off] : 0;
        __syncthreads();
        sh[tid] += v;
        __syncthreads();
    }
    int base = sh[tid] - sum;                     // exclusive prefix of chunk
    for (int i = st; i < en; i++) { rowptr[i] = base; base += deg[i]; }
}

// scatter edges by dst (also records dst per CSR slot for k_ew).
// Mutates rowptr: afterwards rowptr[d] == end(d).
__global__ __launch_bounds__(256) void k_scatter(const int* __restrict__ ei,
                                                 int* __restrict__ rowptr,
                                                 int* __restrict__ e_src,
                                                 int* __restrict__ e_dst) {
    int e = blockIdx.x * 256 + threadIdx.x;
    if (e >= NE) return;
    int d = ei[NE + e];
    int pos = atomicAdd(&rowptr[d], 1);
    e_src[pos] = ei[e];
    e_dst[pos] = d;
}

// ---------- fused BNfin + BN-apply + Linear(128->32)+ReLU + GATw(32->128) + att
__global__ __launch_bounds__(256) void k_fused(const float* __restrict__ x,
                                               const float* __restrict__ stats,
                                               const float* __restrict__ gamma,
                                               const float* __restrict__ beta,
                                               const float* __restrict__ W1, // [32,128]
                                               const float* __restrict__ b1, // [32]
                                               const float* __restrict__ W2, // [128,32]
                                               const float* __restrict__ aS, // [4,32]
                                               const float* __restrict__ aD, // [4,32]
                                               unsigned* __restrict__ h,     // [N,64] packed
                                               float* __restrict__ asrc,     // [N,4]
                                               float* __restrict__ adst) {   // [N,4]
    __shared__ float xb[64 * XS];
    __shared__ float yt[64 * YS];
    __shared__ float w1[32 * 128];
    __shared__ float w2[128 * 32];
    __shared__ float attS[128], attD[128], ssl[256];
    int tid = threadIdx.x;
    int node0 = blockIdx.x * 64;
    int nNodes = min(64, NN - node0);

    for (int i = tid; i < 4096; i += 256) { w1[i] = W1[i]; w2[i] = W2[i]; }
    if (tid < 128) {
        attS[tid] = aS[tid]; attD[tid] = aD[tid];
        float mean = stats[tid] * (1.0f / NN);
        float var  = stats[HCC + tid] * (1.0f / NN) - mean * mean;
        float sc   = gamma[tid] * rsqrtf(var + BN_EPS);
        ssl[tid]       = sc;
        ssl[HCC + tid] = beta[tid] - mean * sc;
    }
    __syncthreads();   // ssl read cross-wave below

    for (int f4 = tid; f4 < nNodes * 32; f4 += 256) {
        int f = f4 * 4; int n = f >> 7; int c = f & 127;
        float4 xv = *(const float4*)(x + (size_t)(node0 + n) * HCC + c);
        float* dst = &xb[n * XS + c];
        dst[0] = xv.x * ssl[c]     + ssl[HCC + c];
        dst[1] = xv.y * ssl[c + 1] + ssl[HCC + c + 1];
        dst[2] = xv.z * ssl[c + 2] + ssl[HCC + c + 2];
        dst[3] = xv.w * ssl[c + 3] + ssl[HCC + c + 3];
    }
    __syncthreads();

    int lane = tid & 63, wv = tid >> 6;
    int n = lane;

    // ---- stage 1: y[n][j0..j0+7]
    {
        int j0 = wv * 8;
        float acc[8];
#pragma unroll
        for (int k = 0; k < 8; k++) acc[k] = b1[j0 + k];
        if (n < nNodes) {
            for (int cb = 0; cb < 128; cb += 4) {
                float xv0 = xb[n * XS + cb],     xv1 = xb[n * XS + cb + 1];
                float xv2 = xb[n * XS + cb + 2], xv3 = xb[n * XS + cb + 3];
#pragma unroll
                for (int k = 0; k < 8; k++) {
                    float4 w = *(const float4*)&w1[(j0 + k) * 128 + cb];
                    acc[k] += xv0 * w.x + xv1 * w.y + xv2 * w.z + xv3 * w.w;
                }
            }
#pragma unroll
            for (int k = 0; k < 8; k++) yt[n * YS + j0 + k] = fmaxf(acc[k], 0.f);
        }
    }
    __syncthreads();

    // ---- stage 2: h[n][k0..k0+31] (bf16), head hd = wv, + attention dots
    if (n < nNodes) {
        int k0 = wv * 32, hd = wv;
        float yreg[32];
#pragma unroll
        for (int j = 0; j < 32; j++) yreg[j] = yt[n * YS + j];
        float sa = 0.f, da = 0.f;
        unsigned* hrow = h + (size_t)(node0 + n) * 64;
        for (int kb = 0; kb < 32; kb += 8) {
            float acck[8];
#pragma unroll
            for (int kk = 0; kk < 8; kk++) acck[kk] = 0.f;
#pragma unroll
            for (int j = 0; j < 32; j += 4) {
#pragma unroll
                for (int kk = 0; kk < 8; kk++) {
                    float4 w = *(const float4*)&w2[(k0 + kb + kk) * 32 + j];
                    acck[kk] += yreg[j] * w.x + yreg[j + 1] * w.y +
                                yreg[j + 2] * w.z + yreg[j + 3] * w.w;
                }
            }
#pragma unroll
            for (int kk = 0; kk < 8; kk++) {
                sa += acck[kk] * attS[hd * 32 + kb + kk];
                da += acck[kk] * attD[hd * 32 + kb + kk];
            }
            uint4 pk;
            pk.x = f2bf_pack(acck[0], acck[1]);
            pk.y = f2bf_pack(acck[2], acck[3]);
            pk.z = f2bf_pack(acck[4], acck[5]);
            pk.w = f2bf_pack(acck[6], acck[7]);
            *(uint4*)(hrow + ((k0 + kb) >> 1)) = pk;
        }
        asrc[(node0 + n) * 4 + hd] = sa;
        adst[(node0 + n) * 4 + hd] = da;
    }
}

// ----------------- edge-parallel attention weights: ew[hd][j] planar, CSR order
__global__ __launch_bounds__(256) void k_ew(const int* __restrict__ e_src,
                                            const int* __restrict__ e_dst,
                                            const float* __restrict__ asrc,
                                            const float* __restrict__ adst,
                                            float* __restrict__ ew) {
    int j = blockIdx.x * 256 + threadIdx.x;
    if (j >= NE) return;
    int hd = blockIdx.y;
    int s = e_src[j], d = e_dst[j];
    float l = asrc[s * 4 + hd] + adst[d * 4 + hd];
    l = l > 0.f ? l : 0.2f * l;
    ew[(size_t)hd * NE + j] = __expf(l);
}

// -------- gather-aggregate: wave per 4 nodes, 16-wide load pipeline.
// Weights stream from ew (indexed by CSR position, independent of e_src).
__global__ __launch_bounds__(256) void k_agg(const int* __restrict__ rowptr,
                                             const int* __restrict__ e_src,
                                             const float* __restrict__ ew,   // [4][E]
                                             const float* __restrict__ asrc,
                                             const float* __restrict__ adst,
                                             const unsigned* __restrict__ h, // [N,64]
                                             const float* __restrict__ gat_b,
                                             float* __restrict__ xo,
                                             float* __restrict__ stats,
                                             int do_stats) {
    int tid = threadIdx.x, lane = tid & 63, wv = tid >> 6;
    int c0 = lane * 2, hd = lane >> 4;
    int nodeBase = blockIdx.x * 16 + wv * 4;
    const float* ewh = ew + (size_t)hd * NE;
    float bs0 = gat_b[c0], bs1 = gat_b[c0 + 1];
    float S0 = 0, S1 = 0, Q0 = 0, Q1 = 0;
    for (int nn = 0; nn < 4; nn++) {
        int d = nodeBase + nn;
        if (d >= NN) break;
        // self loop
        float adv = adst[d * 4 + hd];
        float sl = asrc[d * 4 + hd] + adv; sl = sl > 0.f ? sl : 0.2f * sl;
        float w = __expf(sl);
        unsigned hp = h[(size_t)d * 64 + lane];
        float a0 = w * bf_lo(hp), a1 = w * bf_hi(hp), ws = w;
        int begin = d ? rowptr[d - 1] : 0, end = rowptr[d];
        for (int j = begin; j < end; j += 16) {
            int idx[16]; float wt[16];
#pragma unroll
            for (int t = 0; t < 16; t++) {            // wave-uniform index loads (clamped)
                int jt = j + t;
                int jc = jt < end ? jt : end - 1;
                idx[t] = e_src[jc];
            }
#pragma unroll
            for (int t = 0; t < 16; t++) {            // streaming weights (indep of idx)
                int jt = j + t;
                int jc = jt < end ? jt : end - 1;
                float v = ewh[jc];
                wt[t] = jt < end ? v : 0.f;
            }
            unsigned p[16];
#pragma unroll
            for (int t = 0; t < 16; t++)              // 16 gathers in flight
                p[t] = h[(size_t)idx[t] * 64 + lane];
#pragma unroll
            for (int t = 0; t < 16; t++) {
                a0 += wt[t] * bf_lo(p[t]);
                a1 += wt[t] * bf_hi(p[t]);
                ws += wt[t];
            }
        }
        float inv = 1.0f / (ws + 1e-16f);
        float o0 = a0 * inv + bs0, o1 = a1 * inv + bs1;
        *(float2*)(xo + (size_t)d * HCC + c0) = make_float2(o0, o1);
        S0 += o0; S1 += o1; Q0 += o0 * o0; Q1 += o1 * o1;
    }
    if (!do_stats) return;
    __shared__ float redS[512], redQ[512];
    redS[wv * 128 + c0] = S0; redS[wv * 128 + c0 + 1] = S1;
    redQ[wv * 128 + c0] = Q0; redQ[wv * 128 + c0 + 1] = Q1;
    __syncthreads();
    if (tid < 128) {
        float v = redS[tid] + redS[128 + tid] + redS[256 + tid] + redS[384 + tid];
        atomicAdd(&stats[tid], v);
    } else if (tid < 256) {
        int c = tid - 128;
        float v = redQ[c] + redQ[128 + c] + redQ[256 + c] + redQ[384 + c];
        atomicAdd(&stats[128 + c], v);
    }
}

// ------------------------------------------------------- readout + graph pool
__global__ __launch_bounds__(256) void k_readout(const float* __restrict__ x,
                                                 const int* __restrict__ batch,
                                                 const float* __restrict__ W,  // [10,128]
                                                 const float* __restrict__ bb, // [10]
                                                 float* __restrict__ out) {    // [128,10]
    int i = blockIdx.x * 256 + threadIdx.x;
    if (i >= NN * NOUT) return;
    int n = i / NOUT, j = i - n * NOUT;
    const float* xr = x + (size_t)n * HCC;
    const float* wr = W + j * HCC;
    float acc = bb[j];
#pragma unroll
    for (int c = 0; c < HCC; c += 4) {
        float4 xv = *(const float4*)(xr + c);
        float4 wv = *(const float4*)(wr + c);
        acc += xv.x * wv.x + xv.y * wv.y + xv.z * wv.z + xv.w * wv.w;
    }
    atomicAdd(&out[batch[n] * NOUT + j], acc);
}

extern "C" void kernel_launch(void* const* d_in, const int* in_sizes, int n_in,
                              void* d_out, int out_size, void* d_ws, size_t ws_size,
                              hipStream_t stream) {
    const int*   x_idx = (const int*)d_in[0];
    const int*   ei    = (const int*)d_in[1];
    const int*   batch = (const int*)d_in[2];
    const float* embed = (const float*)d_in[3];
    const float* bn_g  = (const float*)d_in[4];
    const float* bn_b  = (const float*)d_in[5];
    const float* lin_W = (const float*)d_in[6];
    const float* lin_b = (const float*)d_in[7];
    const float* gat_W = (const float*)d_in[8];
    const float* att_s = (const float*)d_in[9];
    const float* att_d = (const float*)d_in[10];
    const float* gat_b = (const float*)d_in[11];
    const float* ro_W  = (const float*)d_in[12];
    const float* ro_b  = (const float*)d_in[13];
    float* out = (float*)d_out;

    // workspace layout
    float*    x     = (float*)d_ws;                        // [N,128] fp32
    unsigned* h     = (unsigned*)(x + (size_t)NN * HCC);   // [N,64] packed bf16
    float*    asrc  = (float*)(h + (size_t)NN * 64);       // [N,4]
    float*    adst  = asrc + (size_t)NN * NHD;             // [N,4]
    float*    stats = adst + (size_t)NN * NHD;             // [4][256]
    float*    ew    = stats + 4 * 2 * HCC;                 // [4][E]
    int*      deg    = (int*)(ew + (size_t)NHD * NE);      // [N]
    int*      rowptr = deg + NN;                           // [N]
    int*      e_src  = rowptr + NN;                        // [E]
    int*      e_dst  = e_src + NE;                         // [E]

    hipMemsetAsync(stats, 0, 4 * 2 * HCC * sizeof(float), stream);
    hipMemsetAsync(deg, 0, NN * sizeof(int), stream);

    k_embed_stats<<<512, 256, 0, stream>>>(x_idx, embed, x, stats);

    // CSR build (graph is static across layers)
    k_hist<<<(NE + 255) / 256, 256, 0, stream>>>(ei, deg);
    k_scan<<<1, 1024, 0, stream>>>(deg, rowptr);
    k_scatter<<<(NE + 255) / 256, 256, 0, stream>>>(ei, rowptr, e_src, e_dst);

    dim3 ewgrid((NE + 255) / 256, NHD);
    for (int l = 0; l < NL; ++l) {
        k_fused<<<(NN + 63) / 64, 256, 0, stream>>>(x, stats + l * 2 * HCC,
                                                    bn_g + l * HCC, bn_b + l * HCC,
                                                    lin_W + l * CC * HCC, lin_b + l * CC,
                                                    gat_W + l * HCC * CC,
                                                    att_s + l * NHD * CC,
                                                    att_d + l * NHD * CC,
                                                    h, asrc, adst);
        k_ew<<<ewgrid, 256, 0, stream>>>(e_src, e_dst, asrc, adst, ew);
        k_agg<<<(NN + 15) / 16, 256, 0, stream>>>(rowptr, e_src, ew, asrc, adst, h,
                                                  gat_b + l * HCC, x,
                                                  stats + (l + 1) * 2 * HCC,
                                                  (l < NL - 1) ? 1 : 0);
    }

    hipMemsetAsync(out, 0, NG * NOUT * sizeof(float), stream);
    k_readout<<<(NN * NOUT + 255) / 256, 256, 0, stream>>>(x, batch, ro_W, ro_b, out);
}